// Round 1
// baseline (2021.567 us; speedup 1.0000x reference)
//
#include <hip/hip_runtime.h>

// Problem constants (from reference setup_inputs)
#define B_    8
#define CIN   512
#define NPIX  16384     // H*W = 128*128
#define CK    256
#define KCTX  64        // context length (softmax axis)
#define CV    256

// ---------------------------------------------------------------------------
// Kernel 1: k_all[b][kk][m] = sum_c Wk[kk][c] * ctx[b][c][m]
//           v_all[b][m][vv] = sum_c Wv[vv][c] * ctx[b][c][m]
// grid = (8 parts, B), block = 256. Parts 0-3 -> k rows, 4-7 -> v rows.
// ---------------------------------------------------------------------------
__global__ __launch_bounds__(256) void kv_kernel(const float* __restrict__ ctx,
                                                 const float* __restrict__ Wk,
                                                 const float* __restrict__ Wv,
                                                 float* __restrict__ k_all,
                                                 float* __restrict__ v_all) {
    __shared__ float ctx_s[CV * KCTX];   // 64 KB: [c][m]
    const int part = blockIdx.x;
    const int b    = blockIdx.y;
    const int t    = threadIdx.x;
    const float* cb = ctx + (size_t)b * CV * KCTX;
    #pragma unroll
    for (int r = 0; r < (CV * KCTX) / 256; ++r) {
        int e = t + 256 * r;
        ctx_s[e] = cb[e];
    }
    __syncthreads();

    const int m = t & 63;
    const int g = t >> 6;        // 0..3
    float acc[16];
    #pragma unroll
    for (int i = 0; i < 16; ++i) acc[i] = 0.f;

    if (part < 4) {
        const int kkbase = part * 64 + g * 16;
        for (int c = 0; c < CV; ++c) {
            float xv = ctx_s[c * 64 + m];
            #pragma unroll
            for (int i = 0; i < 16; ++i)
                acc[i] = fmaf(Wk[(kkbase + i) * CV + c], xv, acc[i]);
        }
        #pragma unroll
        for (int i = 0; i < 16; ++i)
            k_all[((size_t)b * CK + kkbase + i) * KCTX + m] = acc[i];
    } else {
        const int vvbase = (part - 4) * 64 + g * 16;
        for (int c = 0; c < CV; ++c) {
            float xv = ctx_s[c * 64 + m];
            #pragma unroll
            for (int i = 0; i < 16; ++i)
                acc[i] = fmaf(Wv[(vvbase + i) * CV + c], xv, acc[i]);
        }
        #pragma unroll
        for (int i = 0; i < 16; ++i)
            v_all[((size_t)b * KCTX + m) * CV + vvbase + i] = acc[i];
    }
}

// ---------------------------------------------------------------------------
// Kernel 2: fused main chain per (batch, 32-pixel tile).
//   q[kk][n]  = sum_c Wq[kk][c] x[b][c][n]          (LDS qs, [kk][n])
//   sim[n][m] = scale * sum_kk q[kk][n] k_all[b][kk][m]
//   attn      = softmax_m(sim)
//   oa[vv][n] = sum_m attn[n][m] v_all[b][m][vv]    (overwrites qs)
//   out[b][c][n] = sum_vv Wp[c][vv] oa[vv][n]
// block = 256, grid = (NPIX/32, B)
// ---------------------------------------------------------------------------
__global__ __launch_bounds__(256) void fused_kernel(const float* __restrict__ x,
                                                    const float* __restrict__ Wq,
                                                    const float* __restrict__ Wp,
                                                    const float* __restrict__ k_all,
                                                    const float* __restrict__ v_all,
                                                    float* __restrict__ out) {
    __shared__ float qs[CK * 32];       // 32 KB: q as [kk][n], later oa as [vv][n]
    __shared__ float stg[4352];         // 17 KB staging: Wq[256][17] / ks / vs / Wp[8][520]
    __shared__ float xs[16 * 32];       // 2 KB x chunk [cc][n]
    __shared__ float sim_s[32 * 65];    // 8.3 KB attn [n][m], pad 65
    __shared__ float red[320];          // softmax partials

    const int b  = blockIdx.y;
    const int n0 = blockIdx.x * 32;
    const int t  = threadIdx.x;
    const int tx = t & 7;               // n = tx*4 + j
    const int ty = t >> 3;              // 0..31

    // ---------------- Phase 1: q = Wq * x_tile -> qs[kk][n] ----------------
    {
        float acc[8][4];
        #pragma unroll
        for (int i = 0; i < 8; ++i)
            #pragma unroll
            for (int j = 0; j < 4; ++j) acc[i][j] = 0.f;

        for (int c0 = 0; c0 < CIN; c0 += 16) {
            // stage x[b][c0..c0+15][n0..n0+31]  (512 elems)
            {
                int e = t;
                xs[e] = x[((size_t)b * CIN + c0 + (e >> 5)) * NPIX + n0 + (e & 31)];
                e = t + 256;
                xs[e] = x[((size_t)b * CIN + c0 + (e >> 5)) * NPIX + n0 + (e & 31)];
            }
            // stage Wq[0..255][c0..c0+15] -> stg[kk*17+cc]  (4096 elems)
            #pragma unroll
            for (int r = 0; r < 16; ++r) {
                int e = t + 256 * r;
                int kk = e >> 4, cc = e & 15;
                stg[kk * 17 + cc] = Wq[kk * CIN + c0 + cc];
            }
            __syncthreads();
            #pragma unroll
            for (int cc = 0; cc < 16; ++cc) {
                float xv[4];
                #pragma unroll
                for (int j = 0; j < 4; ++j) xv[j] = xs[cc * 32 + tx * 4 + j];
                #pragma unroll
                for (int i = 0; i < 8; ++i) {
                    float wv = stg[(ty * 8 + i) * 17 + cc];
                    #pragma unroll
                    for (int j = 0; j < 4; ++j)
                        acc[i][j] = fmaf(wv, xv[j], acc[i][j]);
                }
            }
            __syncthreads();
        }
        #pragma unroll
        for (int i = 0; i < 8; ++i)
            #pragma unroll
            for (int j = 0; j < 4; ++j)
                qs[(ty * 8 + i) * 32 + tx * 4 + j] = acc[i][j];
        __syncthreads();
    }

    // ---------------- Phase 2: sim + softmax -> sim_s[n][m] ----------------
    {
        const int n2 = t & 31;
        const int mg = t >> 5;          // m = mg*8 + j
        float sa[8];
        #pragma unroll
        for (int j = 0; j < 8; ++j) sa[j] = 0.f;

        for (int k0 = 0; k0 < CK; k0 += 16) {
            #pragma unroll
            for (int r = 0; r < 4; ++r) {
                int e = t + 256 * r;
                stg[e] = k_all[((size_t)b * CK + k0 + (e >> 6)) * KCTX + (e & 63)];
            }
            __syncthreads();
            #pragma unroll
            for (int kk2 = 0; kk2 < 16; ++kk2) {
                float qv = qs[(k0 + kk2) * 32 + n2];
                #pragma unroll
                for (int j = 0; j < 8; ++j)
                    sa[j] = fmaf(qv, stg[kk2 * 64 + mg * 8 + j], sa[j]);
            }
            __syncthreads();
        }
        #pragma unroll
        for (int j = 0; j < 8; ++j) sa[j] *= 0.0625f;   // Ck^-0.5 = 1/16

        // softmax over m (64), rows split across 8 thread-groups
        float pm = sa[0];
        #pragma unroll
        for (int j = 1; j < 8; ++j) pm = fmaxf(pm, sa[j]);
        red[t] = pm;
        __syncthreads();
        if (t < 32) {
            float rm = red[t];
            #pragma unroll
            for (int g = 1; g < 8; ++g) rm = fmaxf(rm, red[t + 32 * g]);
            red[256 + t] = rm;
        }
        __syncthreads();
        float rm = red[256 + n2];
        float ps = 0.f;
        #pragma unroll
        for (int j = 0; j < 8; ++j) { sa[j] = __expf(sa[j] - rm); ps += sa[j]; }
        red[t] = ps;
        __syncthreads();
        if (t < 32) {
            float rs = 0.f;
            #pragma unroll
            for (int g = 0; g < 8; ++g) rs += red[t + 32 * g];
            red[288 + t] = 1.f / rs;
        }
        __syncthreads();
        float inv = red[288 + n2];
        #pragma unroll
        for (int j = 0; j < 8; ++j) sim_s[n2 * 65 + mg * 8 + j] = sa[j] * inv;
        __syncthreads();
    }

    // ---------------- Phase 4: oa[vv][n] = attn * v -> qs ----------------
    {
        float acc2[8][4];
        #pragma unroll
        for (int i = 0; i < 8; ++i)
            #pragma unroll
            for (int j = 0; j < 4; ++j) acc2[i][j] = 0.f;

        for (int m0 = 0; m0 < KCTX; m0 += 16) {
            __syncthreads();   // protect stg from previous readers
            #pragma unroll
            for (int r = 0; r < 16; ++r) {
                int e = t + 256 * r;
                stg[e] = v_all[((size_t)b * KCTX + m0 + (e >> 8)) * CV + (e & 255)];
            }
            __syncthreads();
            #pragma unroll
            for (int mm = 0; mm < 16; ++mm) {
                float av[4];
                #pragma unroll
                for (int j = 0; j < 4; ++j) av[j] = sim_s[(tx * 4 + j) * 65 + m0 + mm];
                #pragma unroll
                for (int i = 0; i < 8; ++i) {
                    float wv = stg[mm * 256 + ty * 8 + i];
                    #pragma unroll
                    for (int j = 0; j < 4; ++j)
                        acc2[i][j] = fmaf(wv, av[j], acc2[i][j]);
                }
            }
        }
        __syncthreads();
        #pragma unroll
        for (int i = 0; i < 8; ++i)
            #pragma unroll
            for (int j = 0; j < 4; ++j)
                qs[(ty * 8 + i) * 32 + tx * 4 + j] = acc2[i][j];
        __syncthreads();
    }

    // ---------------- Phase 5: out = Wp * oa ----------------
    {
        float acc3[16][4];
        #pragma unroll
        for (int i = 0; i < 16; ++i)
            #pragma unroll
            for (int j = 0; j < 4; ++j) acc3[i][j] = 0.f;

        for (int v0 = 0; v0 < CV; v0 += 8) {
            __syncthreads();
            #pragma unroll
            for (int r = 0; r < 16; ++r) {
                int e = t + 256 * r;          // 4096 elems
                int c = e >> 3, w = e & 7;
                stg[w * 520 + c] = Wp[c * CV + v0 + w];
            }
            __syncthreads();
            #pragma unroll
            for (int w = 0; w < 8; ++w) {
                float ov[4];
                #pragma unroll
                for (int j = 0; j < 4; ++j) ov[j] = qs[(v0 + w) * 32 + tx * 4 + j];
                #pragma unroll
                for (int i = 0; i < 16; ++i) {
                    float wp = stg[w * 520 + ty * 16 + i];
                    #pragma unroll
                    for (int j = 0; j < 4; ++j)
                        acc3[i][j] = fmaf(wp, ov[j], acc3[i][j]);
                }
            }
        }
        #pragma unroll
        for (int i = 0; i < 16; ++i)
            #pragma unroll
            for (int j = 0; j < 4; ++j)
                out[((size_t)b * CIN + ty * 16 + i) * NPIX + n0 + tx * 4 + j] = acc3[i][j];
    }
}

// ---------------------------------------------------------------------------
extern "C" void kernel_launch(void* const* d_in, const int* in_sizes, int n_in,
                              void* d_out, int out_size, void* d_ws, size_t ws_size,
                              hipStream_t stream) {
    (void)in_sizes; (void)n_in; (void)out_size; (void)ws_size;
    const float* x   = (const float*)d_in[0];
    const float* ctx = (const float*)d_in[1];
    const float* Wq  = (const float*)d_in[2];
    const float* Wk  = (const float*)d_in[3];
    const float* Wv  = (const float*)d_in[4];
    const float* Wp  = (const float*)d_in[5];
    float* out = (float*)d_out;

    float* k_all = (float*)d_ws;                       // 8*256*64 f32 = 512 KB
    float* v_all = k_all + (size_t)B_ * CK * KCTX;     // 8*64*256 f32 = 512 KB

    kv_kernel<<<dim3(8, B_), 256, 0, stream>>>(ctx, Wk, Wv, k_all, v_all);
    fused_kernel<<<dim3(NPIX / 32, B_), 256, 0, stream>>>(x, Wq, Wp, k_all, v_all, out);
}

// Round 2
// 219.085 us; speedup vs baseline: 9.2273x; 9.2273x over previous
//
#include <hip/hip_runtime.h>
#include <stdint.h>

// Problem constants
#define B_    8
#define CIN   512
#define NPIX  16384
#define CK    256
#define KCTX  64
#define CV    256

typedef _Float16 f16;
typedef _Float16 f16x4 __attribute__((ext_vector_type(4)));
typedef _Float16 f16x8 __attribute__((ext_vector_type(8)));
typedef float    f32x4 __attribute__((ext_vector_type(4)));

#define LOG2E 1.44269504f

// ws layout (bytes)
#define WQ_OFF 0               // 256 KB : Wq fp16 swizzled  [256 m][512 c]
#define WP_OFF 262144          // 256 KB : Wp fp16 swizzled  [512 c][256 v]
#define KT_OFF 524288          // 256 KB : k^T*scale fp16    [b][64 m][256 k]
#define VT_OFF 786432          // 256 KB : v^T fp16          [b][256 v][64 m]

__device__ __forceinline__ void gl_lds16(const void* g, void* l) {
    __builtin_amdgcn_global_load_lds(
        (const __attribute__((address_space(1))) uint32_t*)g,
        (__attribute__((address_space(3))) uint32_t*)l, 16, 0, 0);
}

// ---------------------------------------------------------------------------
// P0: weights -> fp16, fragment-swizzled layouts in ws
// Wq: (mq,c): byte = mq*1024 + (c>>6)*128 + 16*(((c>>3)&7)^(mq&7)) + 2*(c&7)
// Wp: (c,v):  byte = c*512 + (v>>5)*64 + 16*(((v>>3)&3)^((c>>1)&3)) + 2*(v&7)
// ---------------------------------------------------------------------------
__global__ __launch_bounds__(256) void prep_weights(const float* __restrict__ Wq,
                                                    const float* __restrict__ Wp,
                                                    char* __restrict__ ws) {
    int idx = blockIdx.x * 256 + threadIdx.x;   // 0 .. 131071
    {
        int mq = idx >> 9, c = idx & 511;
        int byte = mq * 1024 + ((c >> 6) * 128) + 16 * (((c >> 3) & 7) ^ (mq & 7)) + 2 * (c & 7);
        *(f16*)(ws + WQ_OFF + byte) = (f16)Wq[idx];
    }
    {
        int c = idx >> 8, v = idx & 255;
        int byte = c * 512 + ((v >> 5) * 64) + 16 * ((((v >> 3) & 3)) ^ ((c >> 1) & 3)) + 2 * (v & 7);
        *(f16*)(ws + WP_OFF + byte) = (f16)Wp[idx];
    }
}

// ---------------------------------------------------------------------------
// P1: k^T (scaled) and v^T from context, fp16 swizzled.
// grid = (8 parts, B), block = 256. Parts 0-3 -> k rows, 4-7 -> v rows.
// ---------------------------------------------------------------------------
__global__ __launch_bounds__(256) void kv_kernel(const float* __restrict__ ctx,
                                                 const float* __restrict__ Wk,
                                                 const float* __restrict__ Wv,
                                                 char* __restrict__ ws) {
    __shared__ float ctx_s[CV * KCTX];
    const int part = blockIdx.x;
    const int b    = blockIdx.y;
    const int t    = threadIdx.x;
    const float* cb = ctx + (size_t)b * CV * KCTX;
    #pragma unroll
    for (int r = 0; r < (CV * KCTX) / 256; ++r) { int e = t + 256 * r; ctx_s[e] = cb[e]; }
    __syncthreads();

    const int m = t & 63;
    const int gq = t >> 6;
    float acc[16];
    #pragma unroll
    for (int i = 0; i < 16; ++i) acc[i] = 0.f;

    if (part < 4) {
        const int kkbase = part * 64 + gq * 16;
        for (int c = 0; c < CV; ++c) {
            float xv = ctx_s[c * 64 + m];
            #pragma unroll
            for (int i = 0; i < 16; ++i)
                acc[i] = fmaf(Wk[(kkbase + i) * CV + c], xv, acc[i]);
        }
        char* kt = ws + KT_OFF + b * 32768;
        #pragma unroll
        for (int i = 0; i < 16; ++i) {
            int k = kkbase + i;
            int byte = m * 512 + ((k >> 6) * 128) + 16 * (((k >> 3) & 7) ^ (m & 7)) + 2 * (k & 7);
            *(f16*)(kt + byte) = (f16)(acc[i] * 0.0625f);   // fold scale = Ck^-0.5 = 1/16
        }
    } else {
        const int vvbase = (part - 4) * 64 + gq * 16;
        for (int c = 0; c < CV; ++c) {
            float xv = ctx_s[c * 64 + m];
            #pragma unroll
            for (int i = 0; i < 16; ++i)
                acc[i] = fmaf(Wv[(vvbase + i) * CV + c], xv, acc[i]);
        }
        char* vt = ws + VT_OFF + b * 32768;
        #pragma unroll
        for (int i = 0; i < 16; ++i) {
            int v = vvbase + i;
            int byte = v * 128 + 16 * (((m >> 3) & 7) ^ (v & 7)) + 2 * (m & 7);
            *(f16*)(vt + byte) = (f16)acc[i];
        }
    }
}

// ---------------------------------------------------------------------------
// Fused main kernel: per (batch, 64-pixel tile), 256 threads = 4 waves.
//  ph1: q[256][64]  = Wq * x        (MFMA, K=512, wave-split over Ck rows)
//  ph2: sim[64n][64m] = q^T . kT    (MFMA, K=256, wave-split over n)
//  ph3: softmax over m, in-register
//  ph4: oa[256v][64n] = v^T * attn  (MFMA, K=64, wave-split over v)
//  ph5: out[512c][64n] = Wp * oa    (MFMA, K=256, wave-split over c)
// LDS regions: RA 32KB (wq tile / vT / wp tile), RB 32KB (q_sw / oa_sw),
//              RC 8KB (xs tile / kT tile / attn)
// ---------------------------------------------------------------------------
__global__ __launch_bounds__(256, 2) void fused(const float* __restrict__ x,
                                                const char* __restrict__ ws,
                                                float* __restrict__ out) {
    __shared__ char lds[73728];
    char* RA = lds;
    char* RB = lds + 32768;
    char* RC = lds + 65536;

    const int b  = blockIdx.y;
    const int n0 = blockIdx.x * 64;
    const int t  = threadIdx.x;
    const int w  = t >> 6;
    const int l  = t & 63;
    const int g  = l >> 4;
    const int ln = l & 15;

    const float* xb = x + (size_t)b * (CIN * NPIX) + n0;

    // ---------------- Phase 1: q = Wq * x ----------------
    f32x4 acc1[4][4] = {};   // [mi][ni]
    const char* wq_g = ws + WQ_OFF;
    for (int s = 0; s < 8; ++s) {
        if (s) __syncthreads();
        // stage Wq tile [256 m][64 k] (32 KB), linear (swizzle baked in global)
        #pragma unroll
        for (int r = 0; r < 8; ++r) {
            int ch = t + 256 * r;
            gl_lds16(wq_g + (ch >> 3) * 1024 + s * 128 + (ch & 7) * 16, RA + ch * 16);
        }
        // stage x tile -> xs [64 n][64 c] fp16 swizzled (in-register transpose)
        #pragma unroll
        for (int p = 0; p < 4; ++p) {
            int cg = w + 4 * p;            // 0..15
            int c_loc = cg * 4;
            const float* xrow = xb + (size_t)(s * 64 + c_loc) * NPIX + l;
            f16x4 v4;
            #pragma unroll
            for (int i = 0; i < 4; ++i) v4[i] = (f16)xrow[(size_t)i * NPIX];
            int byte = l * 128 + 16 * (((c_loc >> 3) & 7) ^ (l & 7)) + 2 * (c_loc & 7);
            *(f16x4*)(RC + byte) = v4;
        }
        __syncthreads();
        #pragma unroll
        for (int kk = 0; kk < 2; ++kk) {
            f16x8 a[4], bb[4];
            #pragma unroll
            for (int mi = 0; mi < 4; ++mi) {
                int mq = 64 * w + 16 * mi + ln;
                a[mi] = *(const f16x8*)(RA + mq * 128 + 16 * ((kk * 4 + g) ^ (mq & 7)));
            }
            #pragma unroll
            for (int ni = 0; ni < 4; ++ni) {
                int n = 16 * ni + ln;
                bb[ni] = *(const f16x8*)(RC + n * 128 + 16 * ((kk * 4 + g) ^ (n & 7)));
            }
            #pragma unroll
            for (int mi = 0; mi < 4; ++mi)
                #pragma unroll
                for (int ni = 0; ni < 4; ++ni)
                    acc1[mi][ni] = __builtin_amdgcn_mfma_f32_16x16x32_f16(a[mi], bb[ni], acc1[mi][ni], 0, 0, 0);
        }
    }
    // q scatter -> RB: q_sw [64 n][256 k] fp16 swizzled (b64 packed writes)
    #pragma unroll
    for (int mi = 0; mi < 4; ++mi) {
        #pragma unroll
        for (int ni = 0; ni < 4; ++ni) {
            f16x4 q4;
            #pragma unroll
            for (int r = 0; r < 4; ++r) q4[r] = (f16)acc1[mi][ni][r];
            int n = 16 * ni + ln;
            int byte = n * 512 + w * 128 + 16 * ((2 * mi + (g >> 1)) ^ (n & 7)) + 8 * (g & 1);
            *(f16x4*)(RB + byte) = q4;
        }
    }
    __syncthreads();

    // ---------------- Phase 2: sim^T = q . kT ----------------
    f32x4 d2[4] = {};    // [mc], rows n = 16w+4g+r, cols m = 16mc+ln
    const char* kt_g = ws + KT_OFF + b * 32768;
    for (int s2 = 0; s2 < 4; ++s2) {
        if (s2) __syncthreads();
        #pragma unroll
        for (int r = 0; r < 2; ++r) {
            int ch = t + 256 * r;
            gl_lds16(kt_g + (ch >> 3) * 512 + s2 * 128 + (ch & 7) * 16, RC + ch * 16);
        }
        __syncthreads();
        #pragma unroll
        for (int kk = 0; kk < 2; ++kk) {
            int nq = 16 * w + ln;
            f16x8 aq = *(const f16x8*)(RB + nq * 512 + s2 * 128 + 16 * ((kk * 4 + g) ^ (nq & 7)));
            #pragma unroll
            for (int mc = 0; mc < 4; ++mc) {
                int m = 16 * mc + ln;
                f16x8 bk = *(const f16x8*)(RC + m * 128 + 16 * ((kk * 4 + g) ^ (m & 7)));
                d2[mc] = __builtin_amdgcn_mfma_f32_16x16x32_f16(aq, bk, d2[mc], 0, 0, 0);
            }
        }
    }
    __syncthreads();   // all kT reads done before attn overwrites RC

    // ---------------- Phase 3: softmax over m, in-register ----------------
    float attnv[4][4];   // [mc][r]
    #pragma unroll
    for (int r = 0; r < 4; ++r) {
        float mx = fmaxf(fmaxf(d2[0][r], d2[1][r]), fmaxf(d2[2][r], d2[3][r]));
        #pragma unroll
        for (int off = 1; off < 16; off <<= 1) mx = fmaxf(mx, __shfl_xor(mx, off, 64));
        float sum = 0.f;
        #pragma unroll
        for (int mc = 0; mc < 4; ++mc) {
            float p = __builtin_amdgcn_exp2f((d2[mc][r] - mx) * LOG2E);
            attnv[mc][r] = p; sum += p;
        }
        #pragma unroll
        for (int off = 1; off < 16; off <<= 1) sum += __shfl_xor(sum, off, 64);
        float inv = 1.0f / sum;
        #pragma unroll
        for (int mc = 0; mc < 4; ++mc) attnv[mc][r] *= inv;
    }
    // attn -> RC: at_sw [64 n][64 m] fp16 swizzled
    #pragma unroll
    for (int mc = 0; mc < 4; ++mc) {
        int m = 16 * mc + ln;
        #pragma unroll
        for (int r = 0; r < 4; ++r) {
            int n = 16 * w + 4 * g + r;
            *(f16*)(RC + n * 128 + 16 * ((m >> 3) ^ (n & 7)) + 2 * (m & 7)) = (f16)attnv[mc][r];
        }
    }
    // stage vT -> RA (32 KB)
    const char* vt_g = ws + VT_OFF + b * 32768;
    #pragma unroll
    for (int r = 0; r < 8; ++r) {
        int ch = t + 256 * r;
        gl_lds16(vt_g + (ch >> 3) * 128 + (ch & 7) * 16, RA + ch * 16);
    }
    __syncthreads();

    // ---------------- Phase 4: oa = v^T * attn ----------------
    f32x4 acc4[4][4] = {};   // [vi][ni]
    #pragma unroll
    for (int kk = 0; kk < 2; ++kk) {
        f16x8 av[4], ba[4];
        #pragma unroll
        for (int vi = 0; vi < 4; ++vi) {
            int v = 64 * w + 16 * vi + ln;
            av[vi] = *(const f16x8*)(RA + v * 128 + 16 * ((kk * 4 + g) ^ (v & 7)));
        }
        #pragma unroll
        for (int ni = 0; ni < 4; ++ni) {
            int n = 16 * ni + ln;
            ba[ni] = *(const f16x8*)(RC + n * 128 + 16 * ((kk * 4 + g) ^ (n & 7)));
        }
        #pragma unroll
        for (int vi = 0; vi < 4; ++vi)
            #pragma unroll
            for (int ni = 0; ni < 4; ++ni)
                acc4[vi][ni] = __builtin_amdgcn_mfma_f32_16x16x32_f16(av[vi], ba[ni], acc4[vi][ni], 0, 0, 0);
    }
    // oa scatter -> RB: oa_sw [64 n][256 v] fp16 swizzled
    #pragma unroll
    for (int vi = 0; vi < 4; ++vi) {
        #pragma unroll
        for (int ni = 0; ni < 4; ++ni) {
            f16x4 o4;
            #pragma unroll
            for (int r = 0; r < 4; ++r) o4[r] = (f16)acc4[vi][ni][r];
            int n = 16 * ni + ln;
            int byte = n * 512 + w * 128 + 16 * ((2 * vi + (g >> 1)) ^ (n & 7)) + 8 * (g & 1);
            *(f16x4*)(RB + byte) = o4;
        }
    }
    __syncthreads();   // oa visible; RA free (all vT reads done)

    // ---------------- Phase 5: out = Wp * oa ----------------
    f32x4 acc5[8][4] = {};   // [mi][ni]
    const char* wp_g = ws + WP_OFF;
    for (int s5 = 0; s5 < 8; ++s5) {
        if (s5) __syncthreads();
        #pragma unroll
        for (int r = 0; r < 8; ++r) {
            int ch = t + 256 * r;
            gl_lds16(wp_g + (ch >> 2) * 512 + s5 * 64 + (ch & 3) * 16, RA + ch * 16);
        }
        __syncthreads();
        f16x8 bo[4];
        #pragma unroll
        for (int ni = 0; ni < 4; ++ni) {
            int n = 16 * ni + ln;
            bo[ni] = *(const f16x8*)(RB + n * 512 + (s5 >> 1) * 128 + 16 * (((4 * (s5 & 1) + g)) ^ (n & 7)));
        }
        #pragma unroll
        for (int mi = 0; mi < 8; ++mi) {
            int c = 128 * w + 16 * mi + ln;
            f16x8 ap = *(const f16x8*)(RA + c * 64 + 16 * ((g ^ ((c >> 1) & 3))));
            #pragma unroll
            for (int ni = 0; ni < 4; ++ni)
                acc5[mi][ni] = __builtin_amdgcn_mfma_f32_16x16x32_f16(ap, bo[ni], acc5[mi][ni], 0, 0, 0);
        }
    }
    // store out
    float* ob = out + (size_t)b * (CIN * NPIX) + n0;
    #pragma unroll
    for (int mi = 0; mi < 8; ++mi) {
        #pragma unroll
        for (int ni = 0; ni < 4; ++ni) {
            #pragma unroll
            for (int r = 0; r < 4; ++r) {
                int c = 128 * w + 16 * mi + 4 * g + r;
                ob[(size_t)c * NPIX + 16 * ni + ln] = acc5[mi][ni][r];
            }
        }
    }
}

// ---------------------------------------------------------------------------
extern "C" void kernel_launch(void* const* d_in, const int* in_sizes, int n_in,
                              void* d_out, int out_size, void* d_ws, size_t ws_size,
                              hipStream_t stream) {
    (void)in_sizes; (void)n_in; (void)out_size; (void)ws_size;
    const float* x   = (const float*)d_in[0];
    const float* ctx = (const float*)d_in[1];
    const float* Wq  = (const float*)d_in[2];
    const float* Wk  = (const float*)d_in[3];
    const float* Wv  = (const float*)d_in[4];
    const float* Wp  = (const float*)d_in[5];
    float* out = (float*)d_out;
    char* ws = (char*)d_ws;

    prep_weights<<<dim3(512), 256, 0, stream>>>(Wq, Wp, ws);
    kv_kernel<<<dim3(8, B_), 256, 0, stream>>>(ctx, Wk, Wv, ws);
    fused<<<dim3(NPIX / 64, B_), 256, 0, stream>>>(x, ws, out);
}

// Round 3
// 176.308 us; speedup vs baseline: 11.4661x; 1.2426x over previous
//
#include <hip/hip_runtime.h>
#include <stdint.h>

// Problem constants
#define B_    8
#define CIN   512
#define NPIX  16384
#define CK    256
#define KCTX  64
#define CV    256

typedef _Float16 f16;
typedef _Float16 f16x4 __attribute__((ext_vector_type(4)));
typedef _Float16 f16x8 __attribute__((ext_vector_type(8)));
typedef float    f32x4 __attribute__((ext_vector_type(4)));

#define LOG2E 1.44269504f

// ws layout (bytes), total 1.5 MB
#define WQKT_OFF 0          // 512 KB : Wqk^T*scale f16 swz [b][c-chunk 8][64m x 64c]
#define WPV_OFF  524288     // 512 KB : Wpv f16 swz         [b][c-chunk 4][128c x 64m]
#define KF_OFF   1048576    // 256 KB : k  f16 [b][256 kk][64 m]
#define VM_OFF   1310720    // 256 KB : vm f16 [b][256 v ][64 m]   (v transposed)

__device__ __forceinline__ void gl_lds16(const void* g, void* l) {
    __builtin_amdgcn_global_load_lds(
        (const __attribute__((address_space(1))) uint32_t*)g,
        (__attribute__((address_space(3))) uint32_t*)l, 16, 0, 0);
}

// ---------------------------------------------------------------------------
// prep1: k[row][m] = sum_c Wk[row][c]*ctx[b][c][m];  vm[row][m] = same with Wv
// grid (32, B) x 1024.  p<16 -> k rows, p>=16 -> vm rows (16 rows per block).
// ---------------------------------------------------------------------------
__global__ __launch_bounds__(1024) void prep1(const float* __restrict__ ctx,
                                              const float* __restrict__ Wk,
                                              const float* __restrict__ Wv,
                                              char* __restrict__ ws) {
    const int p = blockIdx.x;
    const int b = blockIdx.y;
    const int t = threadIdx.x;
    const int m = t & 63;
    const int rg = t >> 6;               // wave-uniform
    const int row = (p & 15) * 16 + rg;
    const bool is_k = (p < 16);
    const float* W = (is_k ? Wk : Wv) + (size_t)row * CV;
    const float* cb = ctx + (size_t)b * CV * KCTX + m;
    float acc = 0.f;
    #pragma unroll 8
    for (int c = 0; c < CV; ++c)
        acc = fmaf(W[c], cb[(size_t)c * KCTX], acc);
    char* dst = ws + (is_k ? KF_OFF : VM_OFF) + b * 32768 + (row * 64 + m) * 2;
    *(f16*)dst = (f16)acc;
}

// ---------------------------------------------------------------------------
// prep2: Wqk[c][m] = sum_kk Wq[kk][c]*k[kk][m]  (store *1/16, [m][c] swizzled)
//        Wpv[c][m] = sum_v  Wp[c][v]*vm[v][m]   (store [c][m] swizzled)
// grid (16, B) x 1024.  p<8 -> Wqk (c-base 64p), p>=8 -> Wpv.
// ---------------------------------------------------------------------------
__global__ __launch_bounds__(1024) void prep2(const float* __restrict__ Wq,
                                              const float* __restrict__ Wp,
                                              char* __restrict__ ws) {
    const int p = blockIdx.x;
    const int b = blockIdx.y;
    const int t = threadIdx.x;
    const int m = t & 63;
    const int cg = t >> 6;               // 0..15, wave-uniform
    float acc[4] = {0.f, 0.f, 0.f, 0.f};
    if (p < 8) {
        const int cb = p * 64 + cg * 4;
        const f16* kf = (const f16*)(ws + KF_OFF + b * 32768) + m;
        for (int kk = 0; kk < CK; ++kk) {
            f32x4 wv = *(const f32x4*)(Wq + (size_t)kk * CIN + cb);   // wave-uniform
            float kv = (float)kf[kk * 64];
            #pragma unroll
            for (int i = 0; i < 4; ++i) acc[i] = fmaf(wv[i], kv, acc[i]);
        }
        char* base = ws + WQKT_OFF + b * 65536;
        #pragma unroll
        for (int i = 0; i < 4; ++i) {
            int c = cb + i;
            int byte = (c >> 6) * 8192 + m * 128 + 16 * (((c >> 3) & 7) ^ (m & 7)) + 2 * (c & 7);
            *(f16*)(base + byte) = (f16)(acc[i] * 0.0625f);          // fold scale
        }
    } else {
        const int cb = (p - 8) * 64 + cg * 4;
        const f16* vm = (const f16*)(ws + VM_OFF + b * 32768) + m;
        for (int v = 0; v < CV; v += 4) {
            f32x4 wp[4];
            #pragma unroll
            for (int i = 0; i < 4; ++i)
                wp[i] = *(const f32x4*)(Wp + (size_t)(cb + i) * CV + v);  // wave-uniform
            #pragma unroll
            for (int j = 0; j < 4; ++j) {
                float vv = (float)vm[(v + j) * 64];
                #pragma unroll
                for (int i = 0; i < 4; ++i) acc[i] = fmaf(wp[i][j], vv, acc[i]);
            }
        }
        char* base = ws + WPV_OFF + b * 65536;
        #pragma unroll
        for (int i = 0; i < 4; ++i) {
            int c = cb + i;
            int byte = (c >> 7) * 16384 + (c & 127) * 128 + 16 * (((m >> 3) & 7) ^ (c & 7)) + 2 * (m & 7);
            *(f16*)(base + byte) = (f16)acc[i];
        }
    }
}

// ---------------------------------------------------------------------------
// fused: per (batch, 64-pixel tile), 256 threads = 4 waves.
//   sim_T[m][n] = sum_c Wqk_s[c][m] * x[c][n]   (MFMA, K=512, 8 chunks)
//   attn = softmax_m (in-register, shfl over g)
//   out[c][n]   = sum_m Wpv[c][m] * attn[n][m]  (MFMA, K=64, 4 c-chunks)
// LDS: x_s 2x8K | wq_s 2x8K | at_s 8K | wpv_s 2x16K = 72 KB -> 2 blocks/CU
// ---------------------------------------------------------------------------
__global__ __launch_bounds__(256, 2) void fused(const float* __restrict__ x,
                                                const char* __restrict__ ws,
                                                float* __restrict__ out) {
    __shared__ char lds[73728];
    char* x_s   = lds;              // [n 64][c 64] f16 swizzled, x2
    char* wq_s  = lds + 16384;      // [m 64][c 64] f16 swizzled, x2
    char* at_s  = lds + 32768;      // [n 64][m 64] f16 swizzled
    char* wpv_s = lds + 40960;      // [c 128][m 64] f16 swizzled, x2

    const int b  = blockIdx.y;
    const int n0 = blockIdx.x * 64;
    const int t  = threadIdx.x;
    const int w  = t >> 6, l = t & 63, g = l >> 4, ln = l & 15;

    const float* xb = x + (size_t)b * CIN * NPIX + n0;
    const char* wqkt_g = ws + WQKT_OFF + b * 65536;
    const char* wpv_g  = ws + WPV_OFF  + b * 65536;

    const int n4 = (t & 15) * 4;      // staging: 4 consecutive n
    const int c4 = (t >> 4) * 4;      // staging: 4 consecutive c rows
    const int xsw = 16 * (((c4 >> 3) & 7)) + 2 * (c4 & 7);  // c-part of swizzle

    // ---- prologue: stage chunk 0 ----
    f32x4 xr[4];
    {
        const float* xp = xb + (size_t)c4 * NPIX + n4;
        #pragma unroll
        for (int i = 0; i < 4; ++i) xr[i] = *(const f32x4*)(xp + (size_t)i * NPIX);
    }
    #pragma unroll
    for (int r = 0; r < 2; ++r) {
        int ch = t + 256 * r;
        gl_lds16(wqkt_g + ch * 16, wq_s + ch * 16);
    }
    #pragma unroll
    for (int j = 0; j < 4; ++j) {
        f16x4 v4; v4[0] = (f16)xr[0][j]; v4[1] = (f16)xr[1][j]; v4[2] = (f16)xr[2][j]; v4[3] = (f16)xr[3][j];
        int n = n4 + j;
        *(f16x4*)(x_s + n * 128 + (xsw ^ (16 * (n & 7)))) = v4;
    }
    __syncthreads();

    // ---- sim phase: 8 K-chunks of 64 ----
    f32x4 accs[4] = {};
    const int nB = 16 * w + ln;       // this wave's n (B row / D col)
    for (int s = 0; s < 8; ++s) {
        char* xc = x_s + (s & 1) * 8192;
        char* wc = wq_s + (s & 1) * 8192;
        if (s < 7) {
            char* wn = wq_s + ((s + 1) & 1) * 8192;
            #pragma unroll
            for (int r = 0; r < 2; ++r) {
                int ch = t + 256 * r;
                gl_lds16(wqkt_g + (s + 1) * 8192 + ch * 16, wn + ch * 16);
            }
            const float* xp = xb + (size_t)((s + 1) * 64 + c4) * NPIX + n4;
            #pragma unroll
            for (int i = 0; i < 4; ++i) xr[i] = *(const f32x4*)(xp + (size_t)i * NPIX);
        }
        #pragma unroll
        for (int kk = 0; kk < 2; ++kk) {
            int kb = kk * 4 + g;
            f16x8 bf = *(const f16x8*)(xc + nB * 128 + 16 * (kb ^ (nB & 7)));
            #pragma unroll
            for (int mi = 0; mi < 4; ++mi) {
                int mm = 16 * mi + ln;
                f16x8 af = *(const f16x8*)(wc + mm * 128 + 16 * (kb ^ (mm & 7)));
                accs[mi] = __builtin_amdgcn_mfma_f32_16x16x32_f16(af, bf, accs[mi], 0, 0, 0);
            }
        }
        if (s < 7) {
            char* xn = x_s + ((s + 1) & 1) * 8192;
            #pragma unroll
            for (int j = 0; j < 4; ++j) {
                f16x4 v4; v4[0] = (f16)xr[0][j]; v4[1] = (f16)xr[1][j]; v4[2] = (f16)xr[2][j]; v4[3] = (f16)xr[3][j];
                int n = n4 + j;
                *(f16x4*)(xn + n * 128 + (xsw ^ (16 * (n & 7)))) = v4;
            }
        }
        __syncthreads();
    }

    // ---- softmax over m (64), fully in-register ----
    float mx = accs[0][0];
    #pragma unroll
    for (int mi = 0; mi < 4; ++mi)
        #pragma unroll
        for (int r = 0; r < 4; ++r) mx = fmaxf(mx, accs[mi][r]);
    mx = fmaxf(mx, __shfl_xor(mx, 16, 64));
    mx = fmaxf(mx, __shfl_xor(mx, 32, 64));
    float pv[4][4];
    float sum = 0.f;
    #pragma unroll
    for (int mi = 0; mi < 4; ++mi)
        #pragma unroll
        for (int r = 0; r < 4; ++r) {
            float pe = __builtin_amdgcn_exp2f((accs[mi][r] - mx) * LOG2E);
            pv[mi][r] = pe; sum += pe;
        }
    sum += __shfl_xor(sum, 16, 64);
    sum += __shfl_xor(sum, 32, 64);
    float inv = 1.f / sum;
    // attn -> at_s[n][m] swizzled (each wave writes only its own n rows)
    #pragma unroll
    for (int mi = 0; mi < 4; ++mi) {
        f16x4 a4;
        #pragma unroll
        for (int r = 0; r < 4; ++r) a4[r] = (f16)(pv[mi][r] * inv);
        int m4 = 16 * mi + 4 * g;
        *(f16x4*)(at_s + nB * 128 + 16 * (((m4 >> 3) & 7) ^ (nB & 7)) + 2 * (m4 & 7)) = a4;
    }
    // issue Wpv chunk 0
    #pragma unroll
    for (int r = 0; r < 4; ++r) {
        int ch = t + 256 * r;
        gl_lds16(wpv_g + ch * 16, wpv_s + ch * 16);
    }
    __syncthreads();

    // ---- out phase: 4 c-chunks of 128 ----
    float* ob = out + (size_t)b * CIN * NPIX + n0 + 16 * w + ln;
    #pragma unroll 1
    for (int s5 = 0; s5 < 4; ++s5) {
        char* pc = wpv_s + (s5 & 1) * 16384;
        if (s5 < 3) {
            char* pn = wpv_s + ((s5 + 1) & 1) * 16384;
            #pragma unroll
            for (int r = 0; r < 4; ++r) {
                int ch = t + 256 * r;
                gl_lds16(wpv_g + (s5 + 1) * 16384 + ch * 16, pn + ch * 16);
            }
        }
        f16x8 bf[2];
        #pragma unroll
        for (int kk = 0; kk < 2; ++kk)
            bf[kk] = *(const f16x8*)(at_s + nB * 128 + 16 * ((kk * 4 + g) ^ (nB & 7)));
        #pragma unroll
        for (int mi = 0; mi < 8; ++mi) {
            f32x4 acc = {};
            int cl = 16 * mi + ln;
            #pragma unroll
            for (int kk = 0; kk < 2; ++kk) {
                f16x8 af = *(const f16x8*)(pc + cl * 128 + 16 * ((kk * 4 + g) ^ (cl & 7)));
                acc = __builtin_amdgcn_mfma_f32_16x16x32_f16(af, bf[kk], acc, 0, 0, 0);
            }
            int cg0 = s5 * 128 + 16 * mi + 4 * g;
            #pragma unroll
            for (int r = 0; r < 4; ++r)
                ob[(size_t)(cg0 + r) * NPIX] = acc[r];
        }
        __syncthreads();
    }
}

// ---------------------------------------------------------------------------
extern "C" void kernel_launch(void* const* d_in, const int* in_sizes, int n_in,
                              void* d_out, int out_size, void* d_ws, size_t ws_size,
                              hipStream_t stream) {
    (void)in_sizes; (void)n_in; (void)out_size; (void)ws_size;
    const float* x   = (const float*)d_in[0];
    const float* ctx = (const float*)d_in[1];
    const float* Wq  = (const float*)d_in[2];
    const float* Wk  = (const float*)d_in[3];
    const float* Wv  = (const float*)d_in[4];
    const float* Wp  = (const float*)d_in[5];
    float* out = (float*)d_out;
    char* ws = (char*)d_ws;

    prep1<<<dim3(32, B_), 1024, 0, stream>>>(ctx, Wk, Wv, ws);
    prep2<<<dim3(16, B_), 1024, 0, stream>>>(Wq, Wp, ws);
    fused<<<dim3(NPIX / 64, B_), 256, 0, stream>>>(x, ws, out);
}